// Round 12
// baseline (537.536 us; speedup 1.0000x reference)
//
#include <hip/hip_runtime.h>
#include <hip/hip_bf16.h>
#include <stdint.h>

typedef unsigned short u16;
typedef __bf16 bf16x8 __attribute__((ext_vector_type(8)));
typedef float f32x4 __attribute__((ext_vector_type(4)));

__device__ __forceinline__ float bf2f(unsigned int u) {
  union { float f; unsigned int i; } v; v.i = u << 16; return v.f;
}
__device__ __forceinline__ u16 f2bf(float f) {
  union { float f; unsigned int i; } v; v.f = f;
  unsigned int r = v.i + 0x7fffu + ((v.i >> 16) & 1u);  // RNE
  return (u16)(r >> 16);
}

// fast tanh-form GELU: 0.5u(1+tanh(0.79788456(u+0.044715u^3))) == u * sigmoid(2z)
__device__ __forceinline__ float fast_gelu(float u) {
  const float z = -u * (1.5957691216057308f + 0.07135481282121989f * u * u);
  return u * __builtin_amdgcn_rcpf(1.0f + __expf(z));
}

// async global->LDS, 16B per lane. LDS dest must be wave-uniform base (HW adds lane*16).
__device__ __forceinline__ void gl_lds16(const void* g, void* l) {
  __builtin_amdgcn_global_load_lds(
      (const __attribute__((address_space(1))) unsigned int*)(uintptr_t)g,
      (__attribute__((address_space(3))) unsigned int*)(uintptr_t)l,
      16, 0, 0);
}

// ---------------- elementwise cast f32 -> bf16 ----------------
__global__ __launch_bounds__(256) void k_cast_bf16(const float* __restrict__ in,
                                                   u16* __restrict__ out, int n4) {
  int i = blockIdx.x * blockDim.x + threadIdx.x;
  if (i < n4) {
    float4 v = ((const float4*)in)[i];
    ushort4 o;
    o.x = f2bf(v.x); o.y = f2bf(v.y); o.z = f2bf(v.z); o.w = f2bf(v.w);
    ((ushort4*)out)[i] = o;
  }
}

// ---------------- transpose + cast: W (K x N) f32 -> Wt (N x K) bf16 ----------------
__global__ __launch_bounds__(256) void k_transpose_cast(const float* __restrict__ in,
                                                        u16* __restrict__ out,
                                                        int K, int N) {
  __shared__ float tile[64][65];
  const int k0 = blockIdx.y * 64, n0 = blockIdx.x * 64;
  const int t = threadIdx.x;
#pragma unroll
  for (int i = 0; i < 16; i++) {
    int lin = t + i * 256, kk = lin >> 6, nn = lin & 63;
    tile[kk][nn] = in[(size_t)(k0 + kk) * N + n0 + nn];
  }
  __syncthreads();
#pragma unroll
  for (int i = 0; i < 16; i++) {
    int lin = t + i * 256, nn = lin >> 6, kk = lin & 63;
    out[(size_t)(n0 + nn) * K + k0 + kk] = f2bf(tile[kk][nn]);
  }
}

// ---------------- three 1024x1024 transposes in one dispatch (z selects) ----------------
__global__ __launch_bounds__(256) void k_transpose3(const float* __restrict__ in0,
                                                    const float* __restrict__ in1,
                                                    const float* __restrict__ in2,
                                                    u16* __restrict__ out0,
                                                    u16* __restrict__ out1,
                                                    u16* __restrict__ out2) {
  __shared__ float tile[64][65];
  const float* in = (blockIdx.z == 0) ? in0 : (blockIdx.z == 1) ? in1 : in2;
  u16* out = (blockIdx.z == 0) ? out0 : (blockIdx.z == 1) ? out1 : out2;
  const int k0 = blockIdx.y * 64, n0 = blockIdx.x * 64;
  const int t = threadIdx.x;
#pragma unroll
  for (int i = 0; i < 16; i++) {
    int lin = t + i * 256, kk = lin >> 6, nn = lin & 63;
    tile[kk][nn] = in[(size_t)(k0 + kk) * 1024 + n0 + nn];
  }
  __syncthreads();
#pragma unroll
  for (int i = 0; i < 16; i++) {
    int lin = t + i * 256, nn = lin >> 6, kk = lin & 63;
    out[(size_t)(n0 + nn) * 1024 + k0 + kk] = f2bf(tile[kk][nn]);
  }
}

// ---------------- LayerNorm, f32 input -> bf16 output, wave per row ----------------
template <int RL>
__global__ __launch_bounds__(256) void k_ln_f32(const float* __restrict__ in,
                                                u16* __restrict__ out,
                                                const float* __restrict__ g,
                                                const float* __restrict__ b, int nrows) {
  const int wid = threadIdx.x >> 6, lane = threadIdx.x & 63;
  const int row = blockIdx.x * 4 + wid;
  if (row >= nrows) return;
  constexpr int PER = RL / 64;
  constexpr int NC = PER / 4;
  const float* p = in + (size_t)row * RL;
  float v[PER];
#pragma unroll
  for (int i = 0; i < NC; i++) {
    float4 f = ((const float4*)p)[lane + i * 64];
    v[i * 4 + 0] = f.x; v[i * 4 + 1] = f.y; v[i * 4 + 2] = f.z; v[i * 4 + 3] = f.w;
  }
  float s = 0.f, ss = 0.f;
#pragma unroll
  for (int i = 0; i < PER; i++) { s += v[i]; ss += v[i] * v[i]; }
#pragma unroll
  for (int o = 32; o; o >>= 1) { s += __shfl_xor(s, o, 64); ss += __shfl_xor(ss, o, 64); }
  const float mu = s * (1.0f / RL);
  const float var = ss * (1.0f / RL) - mu * mu;
  const float rs = rsqrtf(var + 1e-5f);
  u16* op = out + (size_t)row * RL;
#pragma unroll
  for (int i = 0; i < NC; i++) {
    ushort4 o;
    int c = (lane + i * 64) * 4;
    o.x = f2bf((v[i * 4 + 0] - mu) * rs * g[c + 0] + b[c + 0]);
    o.y = f2bf((v[i * 4 + 1] - mu) * rs * g[c + 1] + b[c + 1]);
    o.z = f2bf((v[i * 4 + 2] - mu) * rs * g[c + 2] + b[c + 2]);
    o.w = f2bf((v[i * 4 + 3] - mu) * rs * g[c + 3] + b[c + 3]);
    ((ushort4*)op)[lane + i * 64] = o;
  }
}

// ---------------- LayerNorm on bf16 rows of 1024 (src -> dst; in-place safe) ----------------
__global__ __launch_bounds__(256) void k_ln_bf16(const u16* __restrict__ in,
                                                 u16* __restrict__ out,
                                                 const float* __restrict__ g,
                                                 const float* __restrict__ b, int nrows) {
  const int wid = threadIdx.x >> 6, lane = threadIdx.x & 63;
  const int row = blockIdx.x * 4 + wid;
  if (row >= nrows) return;
  const u16* p = in + (size_t)row * 1024;
  float v[16];
#pragma unroll
  for (int i = 0; i < 2; i++) {
    uint4 u = ((const uint4*)p)[lane + i * 64];
    unsigned int w[4] = {u.x, u.y, u.z, u.w};
#pragma unroll
    for (int q = 0; q < 4; q++) {
      v[i * 8 + q * 2 + 0] = bf2f(w[q] & 0xffffu);
      v[i * 8 + q * 2 + 1] = bf2f(w[q] >> 16);
    }
  }
  float s = 0.f, ss = 0.f;
#pragma unroll
  for (int i = 0; i < 16; i++) { s += v[i]; ss += v[i] * v[i]; }
#pragma unroll
  for (int o = 32; o; o >>= 1) { s += __shfl_xor(s, o, 64); ss += __shfl_xor(ss, o, 64); }
  const float mu = s * (1.0f / 1024.f);
  const float var = ss * (1.0f / 1024.f) - mu * mu;
  const float rs = rsqrtf(var + 1e-5f);
  u16* op = out + (size_t)row * 1024;
#pragma unroll
  for (int i = 0; i < 2; i++) {
    uint4 u;
    unsigned int w[4];
#pragma unroll
    for (int q = 0; q < 4; q++) {
      int c = (lane + i * 64) * 8 + q * 2;
      u16 lo = f2bf((v[i * 8 + q * 2 + 0] - mu) * rs * g[c + 0] + b[c + 0]);
      u16 hi = f2bf((v[i * 8 + q * 2 + 1] - mu) * rs * g[c + 1] + b[c + 1]);
      w[q] = (unsigned int)lo | ((unsigned int)hi << 16);
    }
    u.x = w[0]; u.y = w[1]; u.z = w[2]; u.w = w[3];
    ((uint4*)op)[lane + i * 64] = u;
  }
}

// epilogue codes
#define E_BF16 0          // C0(u16) = v
#define E_ADD_BF16 1      // C0(u16) = v + bf(C1(u16))   (C0 may == C1; read-before-write)
#define E_GELU_BF16 4     // C0(u16) = gelu(v + bias)
#define E_BIAS_RESB_OUT 5 // C0(f32) = v + bias + bf(C1(u16))
#define E_KV 6            // cols<1024 -> K row-major (C0); cols>=1024 -> Vt scatter (C1)
#define E_ACC 7           // C0(f32) += v

// ---------------- GEMM v2: 256x256 tile, 8 waves, double-buffered 2-phase, swizzled LDS ----
// R3/R6-proven K-loop (measured best across R4/R5/R7 schedule A/Bs) — DO NOT touch the sync.
// NEW (R12): L2-aware 2D grouping inside each XCD chunk: groups of (rpc bm-rows x 4 bn-cols),
// bn-fastest -> per-group working set ~6 MB (vs 12 MB bn-major), cutting B-panel L2 thrash.
template <int EPI>
__global__ __launch_bounds__(512, 2) void k_gemm2(
    const u16* __restrict__ A, const u16* __restrict__ B,
    int K, int lda, int ldb, int ldc,
    void* C0, void* C1, const float* __restrict__ bias) {
  __shared__ u16 smem[2][2][256 * 64];  // [dbuf][A/B][rows*64] = 128 KiB

  const int tid = threadIdx.x;
  const int lane = tid & 63;
  const int wid = tid >> 6;
  const int wr = wid >> 2;   // 0..1  (M)
  const int wc = wid & 3;    // 0..3  (N)

  // T1: bijective XCD swizzle (8 XCDs) + L2-aware 2D group remap within the chunk
  const int nwg = gridDim.x * gridDim.y;
  const int lid = blockIdx.y * gridDim.x + blockIdx.x;
  const int q = nwg >> 3, r = nwg & 7;
  const int xcd = lid & 7, loc = lid >> 3;
  int bm, bn;
  if (r == 0 && (q % gridDim.x) == 0 && (gridDim.x & 3) == 0) {
    const int rpc = q / gridDim.x;          // bm-rows per XCD chunk
    const int row0 = (xcd * q) / gridDim.x; // chunk's first bm-row (aligned)
    const int grpSz = rpc * 4;
    const int grp = loc / grpSz, li = loc % grpSz;
    bm = (row0 + li / 4) * 256;
    bn = (grp * 4 + (li & 3)) * 256;
  } else {
    const int id = (xcd < r ? xcd * (q + 1) : r * (q + 1) + (xcd - r) * q) + loc;
    bm = (id / gridDim.x) * 256;
    bn = (id % gridDim.x) * 256;
  }

  const u16* Ab = A + (size_t)bm * lda;
  const u16* Bb = B + (size_t)bn * ldb;

  const int r8 = lane >> 3;
  const int ceSw = (((lane & 7) ^ r8) << 3);  // pre-swizzled source col (elements)

  f32x4 acc[8][4];
  const f32x4 vzero = {0.f, 0.f, 0.f, 0.f};
#pragma unroll
  for (int m = 0; m < 8; m++)
#pragma unroll
    for (int n = 0; n < 4; n++) acc[m][n] = vzero;

  const int NK = K / 64;

  auto stage = [&](int bi, int kt) {
    const int k0 = kt * 64;
    u16* As = &smem[bi][0][0];
    u16* Bs = &smem[bi][1][0];
#pragma unroll
    for (int i = 0; i < 4; i++) {
      const int c = wid * 4 + i;
      gl_lds16(Ab + (size_t)(c * 8 + r8) * lda + k0 + ceSw, As + c * 512);
    }
#pragma unroll
    for (int i = 0; i < 4; i++) {
      const int c = wid * 4 + i;
      gl_lds16(Bb + (size_t)(c * 8 + r8) * ldb + k0 + ceSw, Bs + c * 512);
    }
  };

  stage(0, 0);
  __syncthreads();

  int cur = 0;
  for (int kt = 0; kt < NK; kt++) {
    if (kt + 1 < NK) stage(cur ^ 1, kt + 1);  // loads fly under this tile's MFMA
    const u16* As = &smem[cur][0][0];
    const u16* Bs = &smem[cur][1][0];
#pragma unroll
    for (int kk = 0; kk < 2; kk++) {
      const int csw = (kk * 32 + (lane >> 4) * 8) ^ ((lane & 7) << 3);
      bf16x8 af[8], bfv[4];
#pragma unroll
      for (int m = 0; m < 8; m++)
        af[m] = *(const bf16x8*)&As[(wr * 128 + m * 16 + (lane & 15)) * 64 + csw];
#pragma unroll
      for (int n = 0; n < 4; n++)
        bfv[n] = *(const bf16x8*)&Bs[(wc * 64 + n * 16 + (lane & 15)) * 64 + csw];
#pragma unroll
      for (int m = 0; m < 8; m++)
#pragma unroll
        for (int n = 0; n < 4; n++)
          acc[m][n] = __builtin_amdgcn_mfma_f32_16x16x32_bf16(af[m], bfv[n], acc[m][n], 0, 0, 0);
    }
    __syncthreads();
    cur ^= 1;
  }

  const int lr = (lane >> 4) * 4;
  const int lc = lane & 15;
#pragma unroll
  for (int m = 0; m < 8; m++) {
    const int gr0 = bm + wr * 128 + m * 16 + lr;
#pragma unroll
    for (int n = 0; n < 4; n++) {
      const int gc = bn + wc * 64 + n * 16 + lc;
#pragma unroll
      for (int j = 0; j < 4; j++) {
        const int gr = gr0 + j;
        const float v = acc[m][n][j];
        const size_t ci = (size_t)gr * ldc + gc;
        if constexpr (EPI == E_BF16) {
          ((u16*)C0)[ci] = f2bf(v);
        } else if constexpr (EPI == E_ADD_BF16) {
          ((u16*)C0)[ci] = f2bf(v + bf2f(((const u16*)C1)[ci]));
        } else if constexpr (EPI == E_GELU_BF16) {
          ((u16*)C0)[ci] = f2bf(fast_gelu(v + bias[gc]));
        } else if constexpr (EPI == E_BIAS_RESB_OUT) {
          ((float*)C0)[ci] = v + bias[gc] + bf2f(((const u16*)C1)[ci]);
        } else if constexpr (EPI == E_ACC) {
          ((float*)C0)[ci] += v;
        } else if constexpr (EPI == E_KV) {
          // cols 0..1023 -> K buffer (row-major); cols 1024..2047 -> Vt[b][h][d][t]
          if (gc < 1024) {
            ((u16*)C0)[(size_t)gr * 1024 + gc] = f2bf(v);
          } else {
            const int b_ = gr >> 8, t_ = gr & 255, g2 = gc - 1024, h_ = g2 >> 6, d_ = g2 & 63;
            ((u16*)C1)[(((size_t)(b_ * 16 + h_) * 64 + d_) << 8) + t_] = f2bf(v);
          }
        }
      }
    }
  }
}

// ---------------- fused attention: per wave 32 q-rows x full T=256 (R6-proven) ----------------
__global__ __launch_bounds__(256) void k_attn(const u16* __restrict__ qb,
                                              const u16* __restrict__ kb,
                                              const u16* __restrict__ vt,
                                              u16* __restrict__ ob) {
  __shared__ u16 plds[4][32][264];  // 528B row stride; 67.5KB -> 2 blocks/CU
  const int lane = threadIdx.x & 63, wid = threadIdx.x >> 6;
  const int lc = lane & 15, g = lane >> 4;
  const int qt = blockIdx.x;          // 0..7
  const int bh = blockIdx.y;          // 0..255
  const int b = bh >> 4, h = bh & 15;

  const u16* qp = qb + (((size_t)b * 1024 + qt * 128 + wid * 32) << 10) + h * 64;
  const u16* kp = kb + (((size_t)b * 256) << 10) + h * 64;
  const u16* vp = vt + (((size_t)(b * 16 + h)) << 14);  // [64][256]

  f32x4 acc[2][16];
  const f32x4 vzero = {0.f, 0.f, 0.f, 0.f};
#pragma unroll
  for (int m = 0; m < 2; m++)
#pragma unroll
    for (int n = 0; n < 16; n++) acc[m][n] = vzero;

  bf16x8 af[2][2];
#pragma unroll
  for (int m = 0; m < 2; m++)
#pragma unroll
    for (int kk = 0; kk < 2; kk++)
      af[m][kk] = *(const bf16x8*)(qp + ((size_t)(m * 16 + lc) << 10) + kk * 32 + g * 8);

#pragma unroll
  for (int n = 0; n < 16; n++) {
#pragma unroll
    for (int kk = 0; kk < 2; kk++) {
      bf16x8 bv = *(const bf16x8*)(kp + ((size_t)(n * 16 + lc) << 10) + kk * 32 + g * 8);
#pragma unroll
      for (int m = 0; m < 2; m++)
        acc[m][n] = __builtin_amdgcn_mfma_f32_16x16x32_bf16(af[m][kk], bv, acc[m][n], 0, 0, 0);
    }
  }

  const float sc = 0.125f;
#pragma unroll
  for (int m = 0; m < 2; m++) {
#pragma unroll
    for (int j = 0; j < 4; j++) {
      float mx = acc[m][0][j];
#pragma unroll
      for (int n = 1; n < 16; n++) mx = fmaxf(mx, acc[m][n][j]);
#pragma unroll
      for (int o = 1; o < 16; o <<= 1) mx = fmaxf(mx, __shfl_xor(mx, o, 64));
      mx *= sc;
      float sm = 0.f;
#pragma unroll
      for (int n = 0; n < 16; n++) {
        float p = __expf(sc * acc[m][n][j] - mx);
        acc[m][n][j] = p;
        sm += p;
      }
#pragma unroll
      for (int o = 1; o < 16; o <<= 1) sm += __shfl_xor(sm, o, 64);
      const float inv = 1.0f / sm;
      const int rowl = m * 16 + g * 4 + j;
#pragma unroll
      for (int n = 0; n < 16; n++)
        plds[wid][rowl][n * 16 + lc] = f2bf(acc[m][n][j] * inv);
    }
  }

  f32x4 acc2[2][4];
#pragma unroll
  for (int m = 0; m < 2; m++)
#pragma unroll
    for (int n = 0; n < 4; n++) acc2[m][n] = vzero;

#pragma unroll
  for (int kt = 0; kt < 8; kt++) {
    bf16x8 pa[2];
#pragma unroll
    for (int m = 0; m < 2; m++)
      pa[m] = *(const bf16x8*)&plds[wid][m * 16 + lc][kt * 32 + g * 8];
#pragma unroll
    for (int n = 0; n < 4; n++) {
      bf16x8 vv = *(const bf16x8*)(vp + (size_t)(n * 16 + lc) * 256 + kt * 32 + g * 8);
#pragma unroll
      for (int m = 0; m < 2; m++)
        acc2[m][n] = __builtin_amdgcn_mfma_f32_16x16x32_bf16(pa[m], vv, acc2[m][n], 0, 0, 0);
    }
  }

#pragma unroll
  for (int m = 0; m < 2; m++) {
#pragma unroll
    for (int n = 0; n < 4; n++) {
#pragma unroll
      for (int j = 0; j < 4; j++) {
        const int gr = qt * 128 + wid * 32 + m * 16 + g * 4 + j;
        const int gc = h * 64 + n * 16 + lc;
        ob[(((size_t)b * 1024 + gr) << 10) + gc] = f2bf(acc2[m][n][j]);
      }
    }
  }
}

// ---------------------------------- launcher ----------------------------------
extern "C" void kernel_launch(void* const* d_in, const int* in_sizes, int n_in,
                              void* d_out, int out_size, void* d_ws, size_t ws_size,
                              hipStream_t stream) {
  (void)in_sizes; (void)n_in; (void)out_size;
  const float* grid     = (const float*)d_in[0];
  const float* qpos     = (const float*)d_in[1];
  const float* Wq       = (const float*)d_in[2];
  const float* Wk       = (const float*)d_in[3];
  const float* Wv       = (const float*)d_in[4];
  const float* Wo       = (const float*)d_in[5];
  const float* ln_g_g   = (const float*)d_in[6];
  const float* ln_g_b   = (const float*)d_in[7];
  const float* ln_q_g   = (const float*)d_in[8];
  const float* ln_q_b   = (const float*)d_in[9];
  const float* ln_m_g   = (const float*)d_in[10];
  const float* ln_m_b   = (const float*)d_in[11];
  const float* W1       = (const float*)d_in[12];
  const float* b1       = (const float*)d_in[13];
  const float* W2       = (const float*)d_in[14];
  const float* b2       = (const float*)d_in[15];
  float* out = (float*)d_out;

  // ---- workspace: fixed ~87 MB, then a region that hbuf aliases. ----
  char* ws = (char*)d_ws;
  size_t off = 0;
  auto nxt = [&](size_t bytes) { size_t o = off; off += (bytes + 255) & ~(size_t)255; return o; };
  u16* wk_t  = (u16*)(ws + nxt(1024ull * 1024 * 2));   // wv_t must stay adjacent (E_KV)
  u16* wv_t  = (u16*)(ws + nxt(1024ull * 1024 * 2));
  u16* wq_t  = (u16*)(ws + nxt(1024ull * 512 * 2));
  u16* wo_t  = (u16*)(ws + nxt(1024ull * 1024 * 2));
  u16* w1_t  = (u16*)(ws + nxt(4096ull * 1024 * 2));
  u16* w2_t  = (u16*)(ws + nxt(1024ull * 4096 * 2));
  u16* qslot = (u16*)(ws + nxt(16ull * 1024 * 1024 * 2));  // qb -> x (bf16)
  u16* xb    = (u16*)(ws + nxt(16ull * 1024 * 1024 * 2));  // attn -> xn (bf16)
  const size_t regionOff = off;
  u16* gridb = (u16*)(ws + nxt(16ull * 256 * 1024 * 2));   // dead after KV GEMM
  u16* qn    = (u16*)(ws + nxt(16ull * 1024 * 512 * 2));   // dead after Q GEMM
  u16* kb    = (u16*)(ws + nxt(16ull * 256 * 1024 * 2));   // dead after attn
  u16* vt    = (u16*)(ws + nxt(16ull * 16 * 64 * 256 * 2)); // dead after attn
  u16* hbuf  = (u16*)(ws + regionOff);  // aliases gridb..vt (all dead before MLP)

  // single-pass MLP if the region can hold 16384 x 4096 bf16 (128 MB)
  const int HC = (ws_size >= regionOff + (16384ull * 4096 * 2) + (1u << 20)) ? 4096 : 2048;

  u16* qb    = qslot;
  u16* x     = qslot;   // Wo epilogue overwrites qb element-wise (read-before-write per lane)
  u16* attnb = xb;
  u16* xn    = xb;      // LN writes over attn (dead after Wo)

  // 1. casts + weight transposes
  k_cast_bf16<<<4096, 256, 0, stream>>>(grid, gridb, 1048576);
  k_transpose3<<<dim3(16, 16, 3), 256, 0, stream>>>(Wk, Wv, Wo, wk_t, wv_t, wo_t);
  k_transpose_cast<<<dim3(16, 8), 256, 0, stream>>>(Wq, wq_t, 512, 1024);
  k_transpose_cast<<<dim3(64, 16), 256, 0, stream>>>(W1, w1_t, 1024, 4096);
  k_transpose_cast<<<dim3(16, 64), 256, 0, stream>>>(W2, w2_t, 4096, 1024);
  // 2. qn = LN(query_pos)
  k_ln_f32<512><<<4096, 256, 0, stream>>>(qpos, qn, ln_q_g, ln_q_b, 16384);
  // 3. [K_pre | V] = grid @ [Wk | Wv] via gemm2 (957-TF class); K -> kb, V -> Vt; then LN(K)
  k_gemm2<E_KV><<<dim3(8, 16), 512, 0, stream>>>(
      gridb, wk_t, 1024, 1024, 1024, 2048, kb, vt, nullptr);
  k_ln_bf16<<<1024, 256, 0, stream>>>(kb, kb, ln_g_g, ln_g_b, 4096);
  // 4. Q = qn @ Wq (bf16 only)
  k_gemm2<E_BF16><<<dim3(4, 64), 512, 0, stream>>>(
      qn, wq_t, 512, 512, 512, 1024, qb, nullptr, nullptr);
  // 5. attn = softmax(Q Kh^T / 8) Vh -> xb
  k_attn<<<dim3(8, 256), 256, 0, stream>>>(qb, kb, vt, attnb);
  // 6. x = attn @ Wo + Q  (bf16, in place over qb)
  k_gemm2<E_ADD_BF16><<<dim3(4, 64), 512, 0, stream>>>(
      attnb, wo_t, 1024, 1024, 1024, 1024, x, qb, nullptr);
  // 7. xn = LN(x) -> xb (attn dead)
  k_ln_bf16<<<4096, 256, 0, stream>>>(x, xn, ln_m_g, ln_m_b, 16384);
  // 8-9. MLP (single-pass if HC==4096, else 2 chunks with fp32 accumulate)
  for (int c = 0; c < 4096 / HC; c++) {
    k_gemm2<E_GELU_BF16><<<dim3(HC / 256, 64), 512, 0, stream>>>(
        xn, w1_t + (size_t)c * HC * 1024, 1024, 1024, 1024, HC,
        hbuf, nullptr, b1 + c * HC);
    if (c == 0) {
      k_gemm2<E_BIAS_RESB_OUT><<<dim3(4, 64), 512, 0, stream>>>(
          hbuf, w2_t + c * HC, HC, HC, 4096, 1024, out, x, b2);
    } else {
      k_gemm2<E_ACC><<<dim3(4, 64), 512, 0, stream>>>(
          hbuf, w2_t + c * HC, HC, HC, 4096, 1024, out, nullptr, nullptr);
    }
  }
}

// Round 13
// 517.452 us; speedup vs baseline: 1.0388x; 1.0388x over previous
//
#include <hip/hip_runtime.h>
#include <hip/hip_bf16.h>
#include <stdint.h>

typedef unsigned short u16;
typedef __bf16 bf16x8 __attribute__((ext_vector_type(8)));
typedef float f32x4 __attribute__((ext_vector_type(4)));

__device__ __forceinline__ float bf2f(unsigned int u) {
  union { float f; unsigned int i; } v; v.i = u << 16; return v.f;
}
__device__ __forceinline__ u16 f2bf(float f) {
  union { float f; unsigned int i; } v; v.f = f;
  unsigned int r = v.i + 0x7fffu + ((v.i >> 16) & 1u);  // RNE
  return (u16)(r >> 16);
}

// fast tanh-form GELU: 0.5u(1+tanh(0.79788456(u+0.044715u^3))) == u * sigmoid(2z)
__device__ __forceinline__ float fast_gelu(float u) {
  const float z = -u * (1.5957691216057308f + 0.07135481282121989f * u * u);
  return u * __builtin_amdgcn_rcpf(1.0f + __expf(z));
}

// async global->LDS, 16B per lane. LDS dest must be wave-uniform base (HW adds lane*16).
__device__ __forceinline__ void gl_lds16(const void* g, void* l) {
  __builtin_amdgcn_global_load_lds(
      (const __attribute__((address_space(1))) unsigned int*)(uintptr_t)g,
      (__attribute__((address_space(3))) unsigned int*)(uintptr_t)l,
      16, 0, 0);
}

// ---------------- prep mega-kernel: cast + 5 transposes + LN(qpos), one dispatch ----------
// block ranges: [0,4096) cast grid->bf16 | [4096,4864) T(Wk,Wv,Wo) | [4864,4992) T(Wq)
// | [4992,6016) T(W1) | [6016,7040) T(W2) | [7040,11136) LN<512>(qpos)
__global__ __launch_bounds__(256) void k_prep(
    const float* __restrict__ grid, u16* __restrict__ gridb,
    const float* __restrict__ Wk, u16* __restrict__ wk_t,
    const float* __restrict__ Wv, u16* __restrict__ wv_t,
    const float* __restrict__ Wo, u16* __restrict__ wo_t,
    const float* __restrict__ Wq, u16* __restrict__ wq_t,
    const float* __restrict__ W1, u16* __restrict__ w1_t,
    const float* __restrict__ W2, u16* __restrict__ w2_t,
    const float* __restrict__ qpos, u16* __restrict__ qn,
    const float* __restrict__ g512, const float* __restrict__ b512) {
  __shared__ float tile[64][65];
  const int b = blockIdx.x, t = threadIdx.x;

  if (b < 4096) {  // cast: 4096*256 float4 = 4.2M floats
    const int i = b * 256 + t;
    float4 v = ((const float4*)grid)[i];
    ushort4 o;
    o.x = f2bf(v.x); o.y = f2bf(v.y); o.z = f2bf(v.z); o.w = f2bf(v.w);
    ((ushort4*)gridb)[i] = o;
    return;
  }
  if (b >= 7040) {  // LN<512> over qpos: rows 0..16383, 4 rows/block
    const int wid = t >> 6, lane = t & 63;
    const int row = (b - 7040) * 4 + wid;
    const float* p = qpos + (size_t)row * 512;
    float v[8];
#pragma unroll
    for (int i = 0; i < 2; i++) {
      float4 f = ((const float4*)p)[lane + i * 64];
      v[i * 4 + 0] = f.x; v[i * 4 + 1] = f.y; v[i * 4 + 2] = f.z; v[i * 4 + 3] = f.w;
    }
    float s = 0.f, ss = 0.f;
#pragma unroll
    for (int i = 0; i < 8; i++) { s += v[i]; ss += v[i] * v[i]; }
#pragma unroll
    for (int o = 32; o; o >>= 1) { s += __shfl_xor(s, o, 64); ss += __shfl_xor(ss, o, 64); }
    const float mu = s * (1.0f / 512.f);
    const float var = ss * (1.0f / 512.f) - mu * mu;
    const float rs = rsqrtf(var + 1e-5f);
    u16* op = qn + (size_t)row * 512;
#pragma unroll
    for (int i = 0; i < 2; i++) {
      ushort4 o;
      int c = (lane + i * 64) * 4;
      o.x = f2bf((v[i * 4 + 0] - mu) * rs * g512[c + 0] + b512[c + 0]);
      o.y = f2bf((v[i * 4 + 1] - mu) * rs * g512[c + 1] + b512[c + 1]);
      o.z = f2bf((v[i * 4 + 2] - mu) * rs * g512[c + 2] + b512[c + 2]);
      o.w = f2bf((v[i * 4 + 3] - mu) * rs * g512[c + 3] + b512[c + 3]);
      ((ushort4*)op)[lane + i * 64] = o;
    }
    return;
  }
  // transpose branches
  const float* in; u16* out; int K, N, bx, by;
  if (b < 4864) {
    const int t3 = b - 4096, z = t3 >> 8, r = t3 & 255;
    bx = r & 15; by = r >> 4; K = 1024; N = 1024;
    in = (z == 0) ? Wk : (z == 1) ? Wv : Wo;
    out = (z == 0) ? wk_t : (z == 1) ? wv_t : wo_t;
  } else if (b < 4992) {
    const int t4 = b - 4864;
    bx = t4 & 15; by = t4 >> 4; K = 512; N = 1024; in = Wq; out = wq_t;
  } else if (b < 6016) {
    const int t5 = b - 4992;
    bx = t5 % 64; by = t5 / 64; K = 1024; N = 4096; in = W1; out = w1_t;
  } else {
    const int t6 = b - 6016;
    bx = t6 & 15; by = t6 >> 4; K = 4096; N = 1024; in = W2; out = w2_t;
  }
  const int k0 = by * 64, n0 = bx * 64;
#pragma unroll
  for (int i = 0; i < 16; i++) {
    int lin = t + i * 256, kk = lin >> 6, nn = lin & 63;
    tile[kk][nn] = in[(size_t)(k0 + kk) * N + n0 + nn];
  }
  __syncthreads();
#pragma unroll
  for (int i = 0; i < 16; i++) {
    int lin = t + i * 256, nn = lin >> 6, kk = lin & 63;
    out[(size_t)(n0 + nn) * K + k0 + kk] = f2bf(tile[kk][nn]);
  }
}

// ---------------- LayerNorm on bf16 rows of 1024 (src -> dst; in-place safe) ----------------
__global__ __launch_bounds__(256) void k_ln_bf16(const u16* __restrict__ in,
                                                 u16* __restrict__ out,
                                                 const float* __restrict__ g,
                                                 const float* __restrict__ b, int nrows) {
  const int wid = threadIdx.x >> 6, lane = threadIdx.x & 63;
  const int row = blockIdx.x * 4 + wid;
  if (row >= nrows) return;
  const u16* p = in + (size_t)row * 1024;
  float v[16];
#pragma unroll
  for (int i = 0; i < 2; i++) {
    uint4 u = ((const uint4*)p)[lane + i * 64];
    unsigned int w[4] = {u.x, u.y, u.z, u.w};
#pragma unroll
    for (int q = 0; q < 4; q++) {
      v[i * 8 + q * 2 + 0] = bf2f(w[q] & 0xffffu);
      v[i * 8 + q * 2 + 1] = bf2f(w[q] >> 16);
    }
  }
  float s = 0.f, ss = 0.f;
#pragma unroll
  for (int i = 0; i < 16; i++) { s += v[i]; ss += v[i] * v[i]; }
#pragma unroll
  for (int o = 32; o; o >>= 1) { s += __shfl_xor(s, o, 64); ss += __shfl_xor(ss, o, 64); }
  const float mu = s * (1.0f / 1024.f);
  const float var = ss * (1.0f / 1024.f) - mu * mu;
  const float rs = rsqrtf(var + 1e-5f);
  u16* op = out + (size_t)row * 1024;
#pragma unroll
  for (int i = 0; i < 2; i++) {
    uint4 u;
    unsigned int w[4];
#pragma unroll
    for (int q = 0; q < 4; q++) {
      int c = (lane + i * 64) * 8 + q * 2;
      u16 lo = f2bf((v[i * 8 + q * 2 + 0] - mu) * rs * g[c + 0] + b[c + 0]);
      u16 hi = f2bf((v[i * 8 + q * 2 + 1] - mu) * rs * g[c + 1] + b[c + 1]);
      w[q] = (unsigned int)lo | ((unsigned int)hi << 16);
    }
    u.x = w[0]; u.y = w[1]; u.z = w[2]; u.w = w[3];
    ((uint4*)op)[lane + i * 64] = u;
  }
}

// epilogue codes
#define E_BF16 0          // C0(u16) = v
#define E_ADD_BF16 1      // C0(u16) = v + bf(C1(u16))   (C0 may == C1; read-before-write)
#define E_GELU_BF16 4     // C0(u16) = gelu(v + bias)
#define E_BIAS_RESB_OUT 5 // C0(f32) = v + bias + bf(C1(u16))
#define E_ACC 7           // C0(f32) += v

// ---------------- GEMM v2: 256x256 tile, 8 waves, double-buffered 2-phase, swizzled LDS ----
// R3/R6/R11-proven K-loop (measured best across R4/R5/R7 schedule A/Bs). Plain XCD swizzle
// (R12's 2D remap cut FETCH 148->98MB but dur +3us -> fetch not binding; reverted).
template <int EPI>
__global__ __launch_bounds__(512, 2) void k_gemm2(
    const u16* __restrict__ A, const u16* __restrict__ B,
    int K, int lda, int ldb, int ldc,
    void* C0, void* C1, const float* __restrict__ bias) {
  __shared__ u16 smem[2][2][256 * 64];  // [dbuf][A/B][rows*64] = 128 KiB

  const int tid = threadIdx.x;
  const int lane = tid & 63;
  const int wid = tid >> 6;
  const int wr = wid >> 2;   // 0..1  (M)
  const int wc = wid & 3;    // 0..3  (N)

  // T1: bijective XCD swizzle (8 XCDs)
  const int nwg = gridDim.x * gridDim.y;
  const int lid = blockIdx.y * gridDim.x + blockIdx.x;
  const int q = nwg >> 3, r = nwg & 7;
  const int xcd = lid & 7, loc = lid >> 3;
  const int id = (xcd < r ? xcd * (q + 1) : r * (q + 1) + (xcd - r) * q) + loc;
  const int bm = (id / gridDim.x) * 256;
  const int bn = (id % gridDim.x) * 256;

  const u16* Ab = A + (size_t)bm * lda;
  const u16* Bb = B + (size_t)bn * ldb;

  const int r8 = lane >> 3;
  const int ceSw = (((lane & 7) ^ r8) << 3);  // pre-swizzled source col (elements)

  f32x4 acc[8][4];
  const f32x4 vzero = {0.f, 0.f, 0.f, 0.f};
#pragma unroll
  for (int m = 0; m < 8; m++)
#pragma unroll
    for (int n = 0; n < 4; n++) acc[m][n] = vzero;

  const int NK = K / 64;

  auto stage = [&](int bi, int kt) {
    const int k0 = kt * 64;
    u16* As = &smem[bi][0][0];
    u16* Bs = &smem[bi][1][0];
#pragma unroll
    for (int i = 0; i < 4; i++) {
      const int c = wid * 4 + i;
      gl_lds16(Ab + (size_t)(c * 8 + r8) * lda + k0 + ceSw, As + c * 512);
    }
#pragma unroll
    for (int i = 0; i < 4; i++) {
      const int c = wid * 4 + i;
      gl_lds16(Bb + (size_t)(c * 8 + r8) * ldb + k0 + ceSw, Bs + c * 512);
    }
  };

  stage(0, 0);
  __syncthreads();

  int cur = 0;
  for (int kt = 0; kt < NK; kt++) {
    if (kt + 1 < NK) stage(cur ^ 1, kt + 1);  // loads fly under this tile's MFMA
    const u16* As = &smem[cur][0][0];
    const u16* Bs = &smem[cur][1][0];
#pragma unroll
    for (int kk = 0; kk < 2; kk++) {
      const int csw = (kk * 32 + (lane >> 4) * 8) ^ ((lane & 7) << 3);
      bf16x8 af[8], bfv[4];
#pragma unroll
      for (int m = 0; m < 8; m++)
        af[m] = *(const bf16x8*)&As[(wr * 128 + m * 16 + (lane & 15)) * 64 + csw];
#pragma unroll
      for (int n = 0; n < 4; n++)
        bfv[n] = *(const bf16x8*)&Bs[(wc * 64 + n * 16 + (lane & 15)) * 64 + csw];
#pragma unroll
      for (int m = 0; m < 8; m++)
#pragma unroll
        for (int n = 0; n < 4; n++)
          acc[m][n] = __builtin_amdgcn_mfma_f32_16x16x32_bf16(af[m], bfv[n], acc[m][n], 0, 0, 0);
    }
    __syncthreads();
    cur ^= 1;
  }

  const int lr = (lane >> 4) * 4;
  const int lc = lane & 15;
#pragma unroll
  for (int m = 0; m < 8; m++) {
    const int gr0 = bm + wr * 128 + m * 16 + lr;
#pragma unroll
    for (int n = 0; n < 4; n++) {
      const int gc = bn + wc * 64 + n * 16 + lc;
#pragma unroll
      for (int j = 0; j < 4; j++) {
        const int gr = gr0 + j;
        const float v = acc[m][n][j];
        const size_t ci = (size_t)gr * ldc + gc;
        if constexpr (EPI == E_BF16) {
          ((u16*)C0)[ci] = f2bf(v);
        } else if constexpr (EPI == E_ADD_BF16) {
          ((u16*)C0)[ci] = f2bf(v + bf2f(((const u16*)C1)[ci]));
        } else if constexpr (EPI == E_GELU_BF16) {
          ((u16*)C0)[ci] = f2bf(fast_gelu(v + bias[gc]));
        } else if constexpr (EPI == E_BIAS_RESB_OUT) {
          ((float*)C0)[ci] = v + bias[gc] + bf2f(((const u16*)C1)[ci]);
        } else if constexpr (EPI == E_ACC) {
          ((float*)C0)[ci] += v;
        }
      }
    }
  }
}

// ---------------- merged KV + Q projection: one 384-block dispatch ----------------
// blocks [0,128): KV  (A=gridb 4096x1024, B=wkv 2048x1024, E_KV epilogue)  — heavy, first
// blocks [128,384): Q (A=qn 16384x512,  B=wq_t 1024x512,  E_BF16 epilogue) — backfill
// Same gemm2 body/sync; K and epilogue are uniform per block.
__global__ __launch_bounds__(512, 2) void k_gemm_qkv(
    const u16* __restrict__ gridb, const u16* __restrict__ wkv,
    const u16* __restrict__ qn, const u16* __restrict__ wq,
    u16* __restrict__ kb, u16* __restrict__ vt, u16* __restrict__ qb) {
  __shared__ u16 smem[2][2][256 * 64];

  const int tid = threadIdx.x;
  const int lane = tid & 63;
  const int wid = tid >> 6;
  const int wr = wid >> 2;
  const int wc = wid & 3;

  const int bid = blockIdx.x;
  const bool isKV = (bid < 128);
  const u16* A; const u16* B;
  int K, lda, bm, bn;
  if (isKV) {
    A = gridb; B = wkv; K = 1024; lda = 1024;
    bm = (bid >> 3) * 256; bn = (bid & 7) * 256;
  } else {
    const int id = bid - 128;
    A = qn; B = wq; K = 512; lda = 512;
    bm = (id >> 2) * 256; bn = (id & 3) * 256;
  }
  const int ldb = lda;

  const u16* Ab = A + (size_t)bm * lda;
  const u16* Bb = B + (size_t)bn * ldb;

  const int r8 = lane >> 3;
  const int ceSw = (((lane & 7) ^ r8) << 3);

  f32x4 acc[8][4];
  const f32x4 vzero = {0.f, 0.f, 0.f, 0.f};
#pragma unroll
  for (int m = 0; m < 8; m++)
#pragma unroll
    for (int n = 0; n < 4; n++) acc[m][n] = vzero;

  const int NK = K / 64;

  auto stage = [&](int bi, int kt) {
    const int k0 = kt * 64;
    u16* As = &smem[bi][0][0];
    u16* Bs = &smem[bi][1][0];
#pragma unroll
    for (int i = 0; i < 4; i++) {
      const int c = wid * 4 + i;
      gl_lds16(Ab + (size_t)(c * 8 + r8) * lda + k0 + ceSw, As + c * 512);
    }
#pragma unroll
    for (int i = 0; i < 4; i++) {
      const int c = wid * 4 + i;
      gl_lds16(Bb + (size_t)(c * 8 + r8) * ldb + k0 + ceSw, Bs + c * 512);
    }
  };

  stage(0, 0);
  __syncthreads();

  int cur = 0;
  for (int kt = 0; kt < NK; kt++) {
    if (kt + 1 < NK) stage(cur ^ 1, kt + 1);
    const u16* As = &smem[cur][0][0];
    const u16* Bs = &smem[cur][1][0];
#pragma unroll
    for (int kk = 0; kk < 2; kk++) {
      const int csw = (kk * 32 + (lane >> 4) * 8) ^ ((lane & 7) << 3);
      bf16x8 af[8], bfv[4];
#pragma unroll
      for (int m = 0; m < 8; m++)
        af[m] = *(const bf16x8*)&As[(wr * 128 + m * 16 + (lane & 15)) * 64 + csw];
#pragma unroll
      for (int n = 0; n < 4; n++)
        bfv[n] = *(const bf16x8*)&Bs[(wc * 64 + n * 16 + (lane & 15)) * 64 + csw];
#pragma unroll
      for (int m = 0; m < 8; m++)
#pragma unroll
        for (int n = 0; n < 4; n++)
          acc[m][n] = __builtin_amdgcn_mfma_f32_16x16x32_bf16(af[m], bfv[n], acc[m][n], 0, 0, 0);
    }
    __syncthreads();
    cur ^= 1;
  }

  const int lr = (lane >> 4) * 4;
  const int lc = lane & 15;
#pragma unroll
  for (int m = 0; m < 8; m++) {
    const int gr0 = bm + wr * 128 + m * 16 + lr;
#pragma unroll
    for (int n = 0; n < 4; n++) {
      const int gc = bn + wc * 64 + n * 16 + lc;
#pragma unroll
      for (int j = 0; j < 4; j++) {
        const int gr = gr0 + j;
        const float v = acc[m][n][j];
        if (isKV) {
          if (gc < 1024) {
            kb[(size_t)gr * 1024 + gc] = f2bf(v);
          } else {
            const int b_ = gr >> 8, t_ = gr & 255, g2 = gc - 1024, h_ = g2 >> 6, d_ = g2 & 63;
            vt[(((size_t)(b_ * 16 + h_) * 64 + d_) << 8) + t_] = f2bf(v);
          }
        } else {
          qb[(size_t)gr * 1024 + gc] = f2bf(v);
        }
      }
    }
  }
}

// ---------------- fused attention: per wave 32 q-rows x full T=256 (R6-proven) ----------------
__global__ __launch_bounds__(256) void k_attn(const u16* __restrict__ qb,
                                              const u16* __restrict__ kb,
                                              const u16* __restrict__ vt,
                                              u16* __restrict__ ob) {
  __shared__ u16 plds[4][32][264];  // 528B row stride; 67.5KB -> 2 blocks/CU
  const int lane = threadIdx.x & 63, wid = threadIdx.x >> 6;
  const int lc = lane & 15, g = lane >> 4;
  const int qt = blockIdx.x;          // 0..7
  const int bh = blockIdx.y;          // 0..255
  const int b = bh >> 4, h = bh & 15;

  const u16* qp = qb + (((size_t)b * 1024 + qt * 128 + wid * 32) << 10) + h * 64;
  const u16* kp = kb + (((size_t)b * 256) << 10) + h * 64;
  const u16* vp = vt + (((size_t)(b * 16 + h)) << 14);  // [64][256]

  f32x4 acc[2][16];
  const f32x4 vzero = {0.f, 0.f, 0.f, 0.f};
#pragma unroll
  for (int m = 0; m < 2; m++)
#pragma unroll
    for (int n = 0; n < 16; n++) acc[m][n] = vzero;

  bf16x8 af[2][2];
#pragma unroll
  for (int m = 0; m < 2; m++)
#pragma unroll
    for (int kk = 0; kk < 2; kk++)
      af[m][kk] = *(const bf16x8*)(qp + ((size_t)(m * 16 + lc) << 10) + kk * 32 + g * 8);

#pragma unroll
  for (int n = 0; n < 16; n++) {
#pragma unroll
    for (int kk = 0; kk < 2; kk++) {
      bf16x8 bv = *(const bf16x8*)(kp + ((size_t)(n * 16 + lc) << 10) + kk * 32 + g * 8);
#pragma unroll
      for (int m = 0; m < 2; m++)
        acc[m][n] = __builtin_amdgcn_mfma_f32_16x16x32_bf16(af[m][kk], bv, acc[m][n], 0, 0, 0);
    }
  }

  const float sc = 0.125f;
#pragma unroll
  for (int m = 0; m < 2; m++) {
#pragma unroll
    for (int j = 0; j < 4; j++) {
      float mx = acc[m][0][j];
#pragma unroll
      for (int n = 1; n < 16; n++) mx = fmaxf(mx, acc[m][n][j]);
#pragma unroll
      for (int o = 1; o < 16; o <<= 1) mx = fmaxf(mx, __shfl_xor(mx, o, 64));
      mx *= sc;
      float sm = 0.f;
#pragma unroll
      for (int n = 0; n < 16; n++) {
        float p = __expf(sc * acc[m][n][j] - mx);
        acc[m][n][j] = p;
        sm += p;
      }
#pragma unroll
      for (int o = 1; o < 16; o <<= 1) sm += __shfl_xor(sm, o, 64);
      const float inv = 1.0f / sm;
      const int rowl = m * 16 + g * 4 + j;
#pragma unroll
      for (int n = 0; n < 16; n++)
        plds[wid][rowl][n * 16 + lc] = f2bf(acc[m][n][j] * inv);
    }
  }

  f32x4 acc2[2][4];
#pragma unroll
  for (int m = 0; m < 2; m++)
#pragma unroll
    for (int n = 0; n < 4; n++) acc2[m][n] = vzero;

#pragma unroll
  for (int kt = 0; kt < 8; kt++) {
    bf16x8 pa[2];
#pragma unroll
    for (int m = 0; m < 2; m++)
      pa[m] = *(const bf16x8*)&plds[wid][m * 16 + lc][kt * 32 + g * 8];
#pragma unroll
    for (int n = 0; n < 4; n++) {
      bf16x8 vv = *(const bf16x8*)(vp + (size_t)(n * 16 + lc) * 256 + kt * 32 + g * 8);
#pragma unroll
      for (int m = 0; m < 2; m++)
        acc2[m][n] = __builtin_amdgcn_mfma_f32_16x16x32_bf16(pa[m], vv, acc2[m][n], 0, 0, 0);
    }
  }

#pragma unroll
  for (int m = 0; m < 2; m++) {
#pragma unroll
    for (int n = 0; n < 4; n++) {
#pragma unroll
      for (int j = 0; j < 4; j++) {
        const int gr = qt * 128 + wid * 32 + m * 16 + g * 4 + j;
        const int gc = h * 64 + n * 16 + lc;
        ob[(((size_t)b * 1024 + gr) << 10) + gc] = f2bf(acc2[m][n][j]);
      }
    }
  }
}

// ---------------------------------- launcher ----------------------------------
extern "C" void kernel_launch(void* const* d_in, const int* in_sizes, int n_in,
                              void* d_out, int out_size, void* d_ws, size_t ws_size,
                              hipStream_t stream) {
  (void)in_sizes; (void)n_in; (void)out_size;
  const float* grid     = (const float*)d_in[0];
  const float* qpos     = (const float*)d_in[1];
  const float* Wq       = (const float*)d_in[2];
  const float* Wk       = (const float*)d_in[3];
  const float* Wv       = (const float*)d_in[4];
  const float* Wo       = (const float*)d_in[5];
  const float* ln_g_g   = (const float*)d_in[6];
  const float* ln_g_b   = (const float*)d_in[7];
  const float* ln_q_g   = (const float*)d_in[8];
  const float* ln_q_b   = (const float*)d_in[9];
  const float* ln_m_g   = (const float*)d_in[10];
  const float* ln_m_b   = (const float*)d_in[11];
  const float* W1       = (const float*)d_in[12];
  const float* b1       = (const float*)d_in[13];
  const float* W2       = (const float*)d_in[14];
  const float* b2       = (const float*)d_in[15];
  float* out = (float*)d_out;

  // ---- workspace: fixed ~87 MB, then a region that hbuf aliases. ----
  char* ws = (char*)d_ws;
  size_t off = 0;
  auto nxt = [&](size_t bytes) { size_t o = off; off += (bytes + 255) & ~(size_t)255; return o; };
  u16* wk_t  = (u16*)(ws + nxt(1024ull * 1024 * 2));   // wv_t must stay adjacent (KV B-panel)
  u16* wv_t  = (u16*)(ws + nxt(1024ull * 1024 * 2));
  u16* wq_t  = (u16*)(ws + nxt(1024ull * 512 * 2));
  u16* wo_t  = (u16*)(ws + nxt(1024ull * 1024 * 2));
  u16* w1_t  = (u16*)(ws + nxt(4096ull * 1024 * 2));
  u16* w2_t  = (u16*)(ws + nxt(1024ull * 4096 * 2));
  u16* qslot = (u16*)(ws + nxt(16ull * 1024 * 1024 * 2));  // qb -> x (bf16)
  u16* xb    = (u16*)(ws + nxt(16ull * 1024 * 1024 * 2));  // attn -> xn (bf16)
  const size_t regionOff = off;
  u16* gridb = (u16*)(ws + nxt(16ull * 256 * 1024 * 2));   // dead after KV GEMM
  u16* qn    = (u16*)(ws + nxt(16ull * 1024 * 512 * 2));   // dead after Q GEMM
  u16* kb    = (u16*)(ws + nxt(16ull * 256 * 1024 * 2));   // dead after attn
  u16* vt    = (u16*)(ws + nxt(16ull * 16 * 64 * 256 * 2)); // dead after attn
  u16* hbuf  = (u16*)(ws + regionOff);  // aliases gridb..vt (all dead before MLP)

  // single-pass MLP if the region can hold 16384 x 4096 bf16 (128 MB)
  const int HC = (ws_size >= regionOff + (16384ull * 4096 * 2) + (1u << 20)) ? 4096 : 2048;

  u16* qb    = qslot;
  u16* x     = qslot;   // Wo epilogue overwrites qb element-wise (read-before-write per lane)
  u16* attnb = xb;
  u16* xn    = xb;      // LN writes over attn (dead after Wo)

  // 1. prep: cast + all weight transposes + LN(qpos), one dispatch
  k_prep<<<11136, 256, 0, stream>>>(grid, gridb, Wk, wk_t, Wv, wv_t, Wo, wo_t,
                                    Wq, wq_t, W1, w1_t, W2, w2_t,
                                    qpos, qn, ln_q_g, ln_q_b);
  // 2. merged [K_pre | V] and Q projections (384 blocks; KV first); then LN(K)
  k_gemm_qkv<<<384, 512, 0, stream>>>(gridb, wk_t, qn, wq_t, kb, vt, qb);
  k_ln_bf16<<<1024, 256, 0, stream>>>(kb, kb, ln_g_g, ln_g_b, 4096);
  // 3. attn = softmax(Q Kh^T / 8) Vh -> xb
  k_attn<<<dim3(8, 256), 256, 0, stream>>>(qb, kb, vt, attnb);
  // 4. x = attn @ Wo + Q  (bf16, in place over qb)
  k_gemm2<E_ADD_BF16><<<dim3(4, 64), 512, 0, stream>>>(
      attnb, wo_t, 1024, 1024, 1024, 1024, x, qb, nullptr);
  // 5. xn = LN(x) -> xb (attn dead)
  k_ln_bf16<<<4096, 256, 0, stream>>>(x, xn, ln_m_g, ln_m_b, 16384);
  // 6-7. MLP (single-pass if HC==4096, else 2 chunks with fp32 accumulate)
  for (int c = 0; c < 4096 / HC; c++) {
    k_gemm2<E_GELU_BF16><<<dim3(HC / 256, 64), 512, 0, stream>>>(
        xn, w1_t + (size_t)c * HC * 1024, 1024, 1024, 1024, HC,
        hbuf, nullptr, b1 + c * HC);
    if (c == 0) {
      k_gemm2<E_BIAS_RESB_OUT><<<dim3(4, 64), 512, 0, stream>>>(
          hbuf, w2_t + c * HC, HC, HC, 4096, 1024, out, x, b2);
    } else {
      k_gemm2<E_ACC><<<dim3(4, 64), 512, 0, stream>>>(
          hbuf, w2_t + c * HC, HC, HC, 4096, 1024, out, nullptr, nullptr);
    }
  }
}